// Round 3
// baseline (602.123 us; speedup 1.0000x reference)
//
#include <hip/hip_runtime.h>
#include <hip/hip_bf16.h>

// Problem constants
#define Bdim 2
#define Nseq 2048
#define Dmod 1024
#define Hn   16
#define HDim 64

#define XN  (Bdim * Nseq * Dmod)        // 4,194,304
#define WQN (3 * Dmod * Dmod)           // 3,145,728
#define WON (Dmod * Dmod)               // 1,048,576

typedef __attribute__((ext_vector_type(8))) __bf16 bf16x8;
typedef __attribute__((ext_vector_type(4))) __bf16 bf16x4;
typedef __attribute__((ext_vector_type(4))) float  floatx4;

__device__ __forceinline__ floatx4 mfma16(bf16x8 a, bf16x8 b, floatx4 c) {
    return __builtin_amdgcn_mfma_f32_16x16x32_bf16(a, b, c, 0, 0, 0);
}

// ---------------------------------------------------------------------------
// Kernel 0: fp32 -> bf16 conversion of x, W_qkv, W_out into workspace.
// 8,388,608 elements, 4 per thread (float4 in, bf16x4 out).
// ---------------------------------------------------------------------------
__global__ __launch_bounds__(256) void convert_kernel(
    const float* __restrict__ x, const float* __restrict__ wq,
    const float* __restrict__ wo,
    __bf16* __restrict__ xb, __bf16* __restrict__ wqb, __bf16* __restrict__ wob)
{
    int i = (blockIdx.x * 256 + threadIdx.x) * 4;
    const float* src;
    __bf16* dst;
    int off;
    if (i < XN)            { src = x;  dst = xb;  off = i; }
    else if (i < XN + WQN) { src = wq; dst = wqb; off = i - XN; }
    else                   { src = wo; dst = wob; off = i - XN - WQN; }
    float4 v = *(const float4*)(src + off);
    bf16x4 o;
    o.x = (__bf16)v.x; o.y = (__bf16)v.y; o.z = (__bf16)v.z; o.w = (__bf16)v.w;
    *(bf16x4*)(dst + off) = o;
}

// ---------------------------------------------------------------------------
// Kernel 1: QKV projection.  C[m,n] = sum_k x[m,k] * Wq[n,k] + bq[n]
// M = B*N = 4096 tokens, Ncols = 3*D = 3072, K = D = 1024.
// Each wave: 16(M) x 64(N) tile, direct-from-global bf16 MFMA operands.
// Epilogue scatters into Q [B,H,N,HD], K [B,H,N,HD], Vt [B,H,HD,N] (bf16).
// ---------------------------------------------------------------------------
__global__ __launch_bounds__(256) void qkv_kernel(
    const __bf16* __restrict__ x, const __bf16* __restrict__ Wq,
    const float* __restrict__ bq,
    __bf16* __restrict__ qb, __bf16* __restrict__ kb, __bf16* __restrict__ vt)
{
    const int tid  = threadIdx.x;
    const int lane = tid & 63, l16 = lane & 15, quad = lane >> 4;
    const int w    = blockIdx.x * 4 + (tid >> 6);
    const int NT   = (3 * Dmod) / 64;           // 48 n-tiles
    const int m0   = (w / NT) * 16;
    const int n0   = (w % NT) * 64;

    floatx4 z = {0.f, 0.f, 0.f, 0.f};
    floatx4 acc[4];
    #pragma unroll
    for (int s = 0; s < 4; ++s) acc[s] = z;

    const __bf16* arow = x + (m0 + l16) * Dmod + quad * 8;
    const __bf16* brow[4];
    #pragma unroll
    for (int s = 0; s < 4; ++s)
        brow[s] = Wq + (n0 + s * 16 + l16) * Dmod + quad * 8;

    #pragma unroll 4
    for (int k0 = 0; k0 < Dmod; k0 += 32) {
        bf16x8 a = *(const bf16x8*)(arow + k0);
        #pragma unroll
        for (int s = 0; s < 4; ++s) {
            bf16x8 b = *(const bf16x8*)(brow[s] + k0);
            acc[s] = mfma16(a, b, acc[s]);
        }
    }

    // n0 is 64-aligned, so the whole 64-wide tile is one (which, head).
    const int which = n0 / Dmod;
    const int h     = (n0 % Dmod) >> 6;
    const int bi    = m0 >> 11;
    const int pos0  = m0 & (Nseq - 1);

    #pragma unroll
    for (int s = 0; s < 4; ++s) {
        float bias = bq[n0 + s * 16 + l16];
        int hd = s * 16 + l16;
        #pragma unroll
        for (int i = 0; i < 4; ++i) {
            int pos = pos0 + quad * 4 + i;      // C/D row = quad*4 + reg
            __bf16 v = (__bf16)(acc[s][i] + bias);
            if (which == 0)
                qb[((bi * Hn + h) * Nseq + pos) * HDim + hd] = v;
            else if (which == 1)
                kb[((bi * Hn + h) * Nseq + pos) * HDim + hd] = v;
            else
                vt[((bi * Hn + h) * HDim + hd) * Nseq + pos] = v;
        }
    }
}

// ---------------------------------------------------------------------------
// Kernel 2: causal flash attention. One wave per (b,h,16-row Q tile).
// 32-key tiles, online softmax (fp32), causal tile skipping. P transits
// C-layout -> LDS -> A-layout (m120-verified transform). V pre-transposed
// so the PV B-operand is a contiguous 16-B load.
// ---------------------------------------------------------------------------
__global__ __launch_bounds__(256) void attn_kernel(
    const __bf16* __restrict__ qbuf, const __bf16* __restrict__ kbuf,
    const __bf16* __restrict__ vtbuf, __bf16* __restrict__ aout)
{
    __shared__ __align__(16) __bf16 lds[4][16 * 40];

    const int tid  = threadIdx.x;
    const int wiw  = tid >> 6;
    const int lane = tid & 63, l16 = lane & 15, quad = lane >> 4;
    const int w    = blockIdx.x * 4 + wiw;      // 4096 waves total
    const int qt   = w & 127;
    const int bh   = w >> 7;                    // b*16 + h
    const int q0   = qt * 16;

    const __bf16* qs = qbuf  + bh * Nseq * HDim;
    const __bf16* ks = kbuf  + bh * Nseq * HDim;
    const __bf16* vs = vtbuf + bh * HDim * Nseq;

    bf16x8 qf0 = *(const bf16x8*)(qs + (q0 + l16) * HDim + quad * 8);
    bf16x8 qf1 = *(const bf16x8*)(qs + (q0 + l16) * HDim + 32 + quad * 8);

    floatx4 z = {0.f, 0.f, 0.f, 0.f};
    floatx4 o[4];
    float m_i[4], l_i[4];
    #pragma unroll
    for (int s = 0; s < 4; ++s) o[s] = z;
    #pragma unroll
    for (int i = 0; i < 4; ++i) { m_i[i] = -1e30f; l_i[i] = 0.f; }

    const float scale = 0.125f;                 // 1/sqrt(64)
    const int   nkt   = ((q0 + 15) >> 5) + 1;   // 32-key tiles needed (causal)
    __bf16* myp = lds[wiw];

    for (int kt = 0; kt < nkt; ++kt) {
        const int k0 = kt * 32;

        // S = Q K^T for 32 keys: two 16x16 C-tiles, contracting d=64.
        bf16x8 kf0 = *(const bf16x8*)(ks + (k0 + l16) * HDim + quad * 8);
        bf16x8 kf1 = *(const bf16x8*)(ks + (k0 + l16) * HDim + 32 + quad * 8);
        floatx4 s0 = mfma16(qf0, kf0, z);
        s0 = mfma16(qf1, kf1, s0);
        bf16x8 kg0 = *(const bf16x8*)(ks + (k0 + 16 + l16) * HDim + quad * 8);
        bf16x8 kg1 = *(const bf16x8*)(ks + (k0 + 16 + l16) * HDim + 32 + quad * 8);
        floatx4 s1 = mfma16(qf0, kg0, z);
        s1 = mfma16(qf1, kg1, s1);

        float p0[4], p1[4];
        #pragma unroll
        for (int i = 0; i < 4; ++i) {
            const int q = q0 + quad * 4 + i;
            float a0 = (k0 + l16      <= q) ? s0[i] * scale : -1e30f;
            float a1 = (k0 + 16 + l16 <= q) ? s1[i] * scale : -1e30f;
            float rm = fmaxf(a0, a1);
            #pragma unroll
            for (int off = 1; off < 16; off <<= 1)
                rm = fmaxf(rm, __shfl_xor(rm, off));
            float mn    = fmaxf(m_i[i], rm);
            float alpha = __expf(m_i[i] - mn);
            p0[i] = __expf(a0 - mn);
            p1[i] = __expf(a1 - mn);
            float rs = p0[i] + p1[i];
            #pragma unroll
            for (int off = 1; off < 16; off <<= 1)
                rs += __shfl_xor(rs, off);
            l_i[i] = l_i[i] * alpha + rs;
            m_i[i] = mn;
            o[0][i] *= alpha; o[1][i] *= alpha; o[2][i] *= alpha; o[3][i] *= alpha;
        }

        // P: C-layout -> LDS -> A-layout (per-wave region, in-order DS pipe)
        #pragma unroll
        for (int i = 0; i < 4; ++i) {
            const int r = quad * 4 + i;
            myp[r * 40 + l16]      = (__bf16)p0[i];
            myp[r * 40 + 16 + l16] = (__bf16)p1[i];
        }
        asm volatile("s_waitcnt lgkmcnt(0)" ::: "memory");
        bf16x8 pf = *(const bf16x8*)(myp + l16 * 40 + quad * 8);

        // O += P V  (contract 32 keys)
        #pragma unroll
        for (int s = 0; s < 4; ++s) {
            bf16x8 vf = *(const bf16x8*)(vs + (s * 16 + l16) * Nseq + k0 + quad * 8);
            o[s] = mfma16(pf, vf, o[s]);
        }
    }

    // Epilogue: divide by l, write token-major [B,N,D] bf16
    const int bi = bh >> 4, h = bh & 15;
    #pragma unroll
    for (int i = 0; i < 4; ++i) {
        float inv = 1.0f / l_i[i];
        int q = q0 + quad * 4 + i;
        #pragma unroll
        for (int s = 0; s < 4; ++s)
            aout[(bi * Nseq + q) * Dmod + h * 64 + s * 16 + l16] =
                (__bf16)(o[s][i] * inv);
    }
}

// ---------------------------------------------------------------------------
// Kernel 3: output projection.  out[m,n] = sum_k ao[m,k]*Wo[n,k] + bo[n]
// M = 4096, Ncols = 1024, K = 1024.  Output is fp32 (reference dtype).
// ---------------------------------------------------------------------------
__global__ __launch_bounds__(256) void proj_kernel(
    const __bf16* __restrict__ ao, const __bf16* __restrict__ Wo,
    const float* __restrict__ bo, float* __restrict__ out)
{
    const int tid  = threadIdx.x;
    const int lane = tid & 63, l16 = lane & 15, quad = lane >> 4;
    const int w    = blockIdx.x * 4 + (tid >> 6);
    const int NT   = Dmod / 64;                 // 16 n-tiles
    const int m0   = (w / NT) * 16;
    const int n0   = (w % NT) * 64;

    floatx4 z = {0.f, 0.f, 0.f, 0.f};
    floatx4 acc[4];
    #pragma unroll
    for (int s = 0; s < 4; ++s) acc[s] = z;

    const __bf16* arow = ao + (m0 + l16) * Dmod + quad * 8;
    const __bf16* brow[4];
    #pragma unroll
    for (int s = 0; s < 4; ++s)
        brow[s] = Wo + (n0 + s * 16 + l16) * Dmod + quad * 8;

    #pragma unroll 4
    for (int k0 = 0; k0 < Dmod; k0 += 32) {
        bf16x8 a = *(const bf16x8*)(arow + k0);
        #pragma unroll
        for (int s = 0; s < 4; ++s) {
            bf16x8 b = *(const bf16x8*)(brow[s] + k0);
            acc[s] = mfma16(a, b, acc[s]);
        }
    }

    #pragma unroll
    for (int s = 0; s < 4; ++s) {
        float bias = bo[n0 + s * 16 + l16];
        #pragma unroll
        for (int i = 0; i < 4; ++i) {
            int m = m0 + quad * 4 + i;
            out[m * Dmod + n0 + s * 16 + l16] = acc[s][i] + bias;   // fp32 store
        }
    }
}

// ---------------------------------------------------------------------------
extern "C" void kernel_launch(void* const* d_in, const int* in_sizes, int n_in,
                              void* d_out, int out_size, void* d_ws, size_t ws_size,
                              hipStream_t stream) {
    const float* x  = (const float*)d_in[0];   // fp32 per reference
    const float* Wq = (const float*)d_in[1];
    const float* bq = (const float*)d_in[2];
    const float* Wo = (const float*)d_in[3];
    const float* bo = (const float*)d_in[4];
    float* out = (float*)d_out;                // fp32 output (reference dtype)

    // Workspace layout (bf16 elements):
    //   xb 4M | wqb 3M | wob 1M | qb 4M | kb 4M | vt 4M | ao 4M  = 48 MB
    __bf16* ws  = (__bf16*)d_ws;
    __bf16* xb  = ws;
    __bf16* wqb = ws + (size_t)XN;
    __bf16* wob = wqb + (size_t)WQN;
    __bf16* qb  = wob + (size_t)WON;
    const size_t SZ = (size_t)Bdim * Hn * Nseq * HDim;  // 4,194,304
    __bf16* kb  = qb + SZ;
    __bf16* vt  = kb + SZ;
    __bf16* ao  = vt + SZ;

    // (XN+WQN+WON)/4/256 = 8192 blocks
    convert_kernel<<<dim3(8192), dim3(256), 0, stream>>>(x, Wq, Wo, xb, wqb, wob);
    // (4096/16)*(3072/64) = 12288 waves -> 3072 blocks
    qkv_kernel<<<dim3(3072), dim3(256), 0, stream>>>(xb, wqb, bq, qb, kb, vt);
    // 32 (b,h) * 128 q-tiles = 4096 waves -> 1024 blocks
    attn_kernel<<<dim3(1024), dim3(256), 0, stream>>>(qb, kb, vt, ao);
    // (4096/16)*(1024/64) = 4096 waves -> 1024 blocks
    proj_kernel<<<dim3(1024), dim3(256), 0, stream>>>(ao, wob, bo, out);
}

// Round 5
// 394.874 us; speedup vs baseline: 1.5248x; 1.5248x over previous
//
#include <hip/hip_runtime.h>
#include <hip/hip_bf16.h>

// Problem constants
#define Bdim 2
#define Nseq 2048
#define Dmod 1024
#define Hn   16
#define HDim 64

#define XN  (Bdim * Nseq * Dmod)        // 4,194,304
#define WQN (3 * Dmod * Dmod)           // 3,145,728
#define WON (Dmod * Dmod)               // 1,048,576

typedef __attribute__((ext_vector_type(8))) __bf16 bf16x8;
typedef __attribute__((ext_vector_type(4))) __bf16 bf16x4;
typedef __attribute__((ext_vector_type(4))) float  floatx4;

__device__ __forceinline__ floatx4 mfma16(bf16x8 a, bf16x8 b, floatx4 c) {
    return __builtin_amdgcn_mfma_f32_16x16x32_bf16(a, b, c, 0, 0, 0);
}

// native v_exp_f32 computes 2^x
__device__ __forceinline__ float exp2v(float x) {
    return __builtin_amdgcn_exp2f(x);
}

// ---------------------------------------------------------------------------
// Kernel 0: fp32 -> bf16 conversion of x, W_qkv, W_out into workspace.
// ---------------------------------------------------------------------------
__global__ __launch_bounds__(256) void convert_kernel(
    const float* __restrict__ x, const float* __restrict__ wq,
    const float* __restrict__ wo,
    __bf16* __restrict__ xb, __bf16* __restrict__ wqb, __bf16* __restrict__ wob)
{
    int i = (blockIdx.x * 256 + threadIdx.x) * 4;
    const float* src;
    __bf16* dst;
    int off;
    if (i < XN)            { src = x;  dst = xb;  off = i; }
    else if (i < XN + WQN) { src = wq; dst = wqb; off = i - XN; }
    else                   { src = wo; dst = wob; off = i - XN - WQN; }
    float4 v = *(const float4*)(src + off);
    bf16x4 o;
    o.x = (__bf16)v.x; o.y = (__bf16)v.y; o.z = (__bf16)v.z; o.w = (__bf16)v.w;
    *(bf16x4*)(dst + off) = o;
}

// ---------------------------------------------------------------------------
// Kernel 1: QKV projection. 32(M) x 64(N) per wave: 2 A-frags share each
// B-frag -> half the B-side L2/L3 traffic of 16x64.
// Scatters into Q [B,H,N,HD], K [B,H,N,HD], Vt [B,H,HD,N] (bf16).
// ---------------------------------------------------------------------------
__global__ __launch_bounds__(256) void qkv_kernel(
    const __bf16* __restrict__ x, const __bf16* __restrict__ Wq,
    const float* __restrict__ bq,
    __bf16* __restrict__ qb, __bf16* __restrict__ kb, __bf16* __restrict__ vt)
{
    const int tid  = threadIdx.x;
    const int lane = tid & 63, l16 = lane & 15, quad = lane >> 4;
    const int w    = blockIdx.x * 4 + (tid >> 6);
    const int NT   = (3 * Dmod) / 64;           // 48 n-tiles
    const int m0   = (w / NT) * 32;
    const int n0   = (w % NT) * 64;

    floatx4 z = {0.f, 0.f, 0.f, 0.f};
    floatx4 acc[2][4];
    #pragma unroll
    for (int r = 0; r < 2; ++r)
        #pragma unroll
        for (int s = 0; s < 4; ++s) acc[r][s] = z;

    const __bf16* a0 = x + (m0 + l16) * Dmod + quad * 8;
    const __bf16* a1 = x + (m0 + 16 + l16) * Dmod + quad * 8;
    const __bf16* brow[4];
    #pragma unroll
    for (int s = 0; s < 4; ++s)
        brow[s] = Wq + (n0 + s * 16 + l16) * Dmod + quad * 8;

    #pragma unroll 2
    for (int k0 = 0; k0 < Dmod; k0 += 32) {
        bf16x8 av0 = *(const bf16x8*)(a0 + k0);
        bf16x8 av1 = *(const bf16x8*)(a1 + k0);
        #pragma unroll
        for (int s = 0; s < 4; ++s) {
            bf16x8 b = *(const bf16x8*)(brow[s] + k0);
            acc[0][s] = mfma16(av0, b, acc[0][s]);
            acc[1][s] = mfma16(av1, b, acc[1][s]);
        }
    }

    const int which = n0 / Dmod;
    const int h     = (n0 % Dmod) >> 6;
    const int bi    = m0 >> 11;
    const int pos0  = m0 & (Nseq - 1);

    #pragma unroll
    for (int s = 0; s < 4; ++s) {
        float bias = bq[n0 + s * 16 + l16];
        int hd = s * 16 + l16;
        #pragma unroll
        for (int r = 0; r < 2; ++r)
            #pragma unroll
            for (int i = 0; i < 4; ++i) {
                int pos = pos0 + r * 16 + quad * 4 + i;
                __bf16 v = (__bf16)(acc[r][s][i] + bias);
                if (which == 0)
                    qb[((bi * Hn + h) * Nseq + pos) * HDim + hd] = v;
                else if (which == 1)
                    kb[((bi * Hn + h) * Nseq + pos) * HDim + hd] = v;
                else
                    vt[((bi * Hn + h) * HDim + hd) * Nseq + pos] = v;
            }
    }
}

// ---------------------------------------------------------------------------
// Kernel 2: causal flash attention, S^T formulation.
//   S^T = K·Q^T  (A=K rows, B=Q rows)  -> C col=l16=q, row=key
//   => softmax per-lane local (16 scores/lane for ONE q row) + 2 shuffles.
//   O^T = V^T·P^T (A=V^T, B=P)         -> alpha rescale fully in-lane.
// 64 keys/iter; only the last iter needs the causal mask (k0+63 < q0 before).
// Balanced mapping: qt = (b>>5) + 32*wiw spreads causal work across blocks.
// ---------------------------------------------------------------------------
__global__ __launch_bounds__(256) void attn_kernel(
    const __bf16* __restrict__ qbuf, const __bf16* __restrict__ kbuf,
    const __bf16* __restrict__ vtbuf, __bf16* __restrict__ aout)
{
    __shared__ __align__(16) __bf16 lds[4][16 * 72];

    const int tid  = threadIdx.x;
    const int wiw  = tid >> 6;
    const int lane = tid & 63, l16 = lane & 15, quad = lane >> 4;
    const int b    = blockIdx.x;
    const int bh   = b & 31;
    const int qt   = (b >> 5) + 32 * wiw;       // balanced causal work
    const int q0   = qt * 16;

    const __bf16* qs = qbuf  + bh * Nseq * HDim;
    const __bf16* ks = kbuf  + bh * Nseq * HDim;
    const __bf16* vs = vtbuf + bh * HDim * Nseq;

    // Q as B-operand: lane l16 = q row, k = d = quad*8+j
    bf16x8 qf0 = *(const bf16x8*)(qs + (q0 + l16) * HDim + quad * 8);
    bf16x8 qf1 = *(const bf16x8*)(qs + (q0 + l16) * HDim + 32 + quad * 8);

    floatx4 z = {0.f, 0.f, 0.f, 0.f};
    floatx4 o[4];
    #pragma unroll
    for (int s = 0; s < 4; ++s) o[s] = z;
    float m_i = -1e30f, l_i = 0.f;              // per-lane: q = q0 + l16

    const float C   = 0.125f * 1.44269504f;     // scale * log2(e)
    const int   nkt = (q0 >> 6) + 1;            // 64-key tiles
    __bf16* myp = lds[wiw];

    for (int kt = 0; kt < nkt; ++kt) {
        const int k0 = kt * 64;
        const bool last = (kt == nkt - 1);

        // S^T: 4 tiles of 16 keys. A=K (m=key), B=Q (n=q).
        floatx4 st[4];
        #pragma unroll
        for (int t = 0; t < 4; ++t) {
            const __bf16* kp = ks + (k0 + t * 16 + l16) * HDim + quad * 8;
            bf16x8 kf0 = *(const bf16x8*)(kp);
            bf16x8 kf1 = *(const bf16x8*)(kp + 32);
            st[t] = mfma16(kf0, qf0, z);
            st[t] = mfma16(kf1, qf1, st[t]);
        }

        // scores (log2 domain); lane holds keys {16t+quad*4+i} for q=q0+l16
        float a[16];
        #pragma unroll
        for (int t = 0; t < 4; ++t)
            #pragma unroll
            for (int i = 0; i < 4; ++i) {
                float v = st[t][i] * C;
                if (last) {
                    int key = k0 + t * 16 + quad * 4 + i;
                    v = (key <= q0 + l16) ? v : -1e30f;
                }
                a[t * 4 + i] = v;
            }

        // row max: 15 local + 2 cross-quad shuffles
        float mx = a[0];
        #pragma unroll
        for (int j = 1; j < 16; ++j) mx = fmaxf(mx, a[j]);
        mx = fmaxf(mx, __shfl_xor(mx, 16));
        mx = fmaxf(mx, __shfl_xor(mx, 32));

        float mn    = fmaxf(m_i, mx);
        float alpha = exp2v(m_i - mn);

        float p[16], rs = 0.f;
        #pragma unroll
        for (int j = 0; j < 16; ++j) { p[j] = exp2v(a[j] - mn); rs += p[j]; }
        rs += __shfl_xor(rs, 16);
        rs += __shfl_xor(rs, 32);
        l_i = l_i * alpha + rs;
        m_i = mn;

        #pragma unroll
        for (int s = 0; s < 4; ++s)
            #pragma unroll
            for (int i = 0; i < 4; ++i) o[s][i] *= alpha;   // alpha in-lane

        // P -> LDS: row q (=l16), col = key offset 16t+quad*4+i
        #pragma unroll
        for (int t = 0; t < 4; ++t) {
            bf16x4 pk;
            pk.x = (__bf16)p[t * 4 + 0]; pk.y = (__bf16)p[t * 4 + 1];
            pk.z = (__bf16)p[t * 4 + 2]; pk.w = (__bf16)p[t * 4 + 3];
            *(bf16x4*)(myp + l16 * 72 + t * 16 + quad * 4) = pk;
        }
        asm volatile("s_waitcnt lgkmcnt(0)" ::: "memory");
        // P as B-operand: lane l16 = q, k = key offset quad*8+j
        bf16x8 pf0 = *(const bf16x8*)(myp + l16 * 72 + quad * 8);
        bf16x8 pf1 = *(const bf16x8*)(myp + l16 * 72 + 32 + quad * 8);

        // O^T += V^T P^T : A=V^T (m=d, k=key), contiguous vt loads
        #pragma unroll
        for (int s = 0; s < 4; ++s) {
            const __bf16* vp = vs + (s * 16 + l16) * Nseq + k0 + quad * 8;
            bf16x8 vf0 = *(const bf16x8*)(vp);
            bf16x8 vf1 = *(const bf16x8*)(vp + 32);
            o[s] = mfma16(vf0, pf0, o[s]);
            o[s] = mfma16(vf1, pf1, o[s]);
        }
    }

    // Epilogue: O^T tile s: row = d = s*16+quad*4+i, col = q = q0+l16 (in-lane l)
    const float inv = 1.0f / l_i;
    const int bi = bh >> 4, h = bh & 15;
    #pragma unroll
    for (int s = 0; s < 4; ++s) {
        bf16x4 ov;
        ov.x = (__bf16)(o[s][0] * inv); ov.y = (__bf16)(o[s][1] * inv);
        ov.z = (__bf16)(o[s][2] * inv); ov.w = (__bf16)(o[s][3] * inv);
        *(bf16x4*)(aout + ((size_t)(bi * Nseq + q0 + l16)) * Dmod
                   + h * 64 + s * 16 + quad * 4) = ov;
    }
}

// ---------------------------------------------------------------------------
// Kernel 3: output projection, 32x64 per wave, fp32 out.
// ---------------------------------------------------------------------------
__global__ __launch_bounds__(256) void proj_kernel(
    const __bf16* __restrict__ ao, const __bf16* __restrict__ Wo,
    const float* __restrict__ bo, float* __restrict__ out)
{
    const int tid  = threadIdx.x;
    const int lane = tid & 63, l16 = lane & 15, quad = lane >> 4;
    const int w    = blockIdx.x * 4 + (tid >> 6);
    const int NT   = Dmod / 64;                 // 16 n-tiles
    const int m0   = (w / NT) * 32;
    const int n0   = (w % NT) * 64;

    floatx4 z = {0.f, 0.f, 0.f, 0.f};
    floatx4 acc[2][4];
    #pragma unroll
    for (int r = 0; r < 2; ++r)
        #pragma unroll
        for (int s = 0; s < 4; ++s) acc[r][s] = z;

    const __bf16* a0 = ao + (m0 + l16) * Dmod + quad * 8;
    const __bf16* a1 = ao + (m0 + 16 + l16) * Dmod + quad * 8;
    const __bf16* brow[4];
    #pragma unroll
    for (int s = 0; s < 4; ++s)
        brow[s] = Wo + (n0 + s * 16 + l16) * Dmod + quad * 8;

    #pragma unroll 2
    for (int k0 = 0; k0 < Dmod; k0 += 32) {
        bf16x8 av0 = *(const bf16x8*)(a0 + k0);
        bf16x8 av1 = *(const bf16x8*)(a1 + k0);
        #pragma unroll
        for (int s = 0; s < 4; ++s) {
            bf16x8 b = *(const bf16x8*)(brow[s] + k0);
            acc[0][s] = mfma16(av0, b, acc[0][s]);
            acc[1][s] = mfma16(av1, b, acc[1][s]);
        }
    }

    #pragma unroll
    for (int s = 0; s < 4; ++s) {
        float bias = bo[n0 + s * 16 + l16];
        #pragma unroll
        for (int r = 0; r < 2; ++r)
            #pragma unroll
            for (int i = 0; i < 4; ++i) {
                int m = m0 + r * 16 + quad * 4 + i;
                out[m * Dmod + n0 + s * 16 + l16] = acc[r][s][i] + bias;
            }
    }
}

// ---------------------------------------------------------------------------
extern "C" void kernel_launch(void* const* d_in, const int* in_sizes, int n_in,
                              void* d_out, int out_size, void* d_ws, size_t ws_size,
                              hipStream_t stream) {
    const float* x  = (const float*)d_in[0];
    const float* Wq = (const float*)d_in[1];
    const float* bq = (const float*)d_in[2];
    const float* Wo = (const float*)d_in[3];
    const float* bo = (const float*)d_in[4];
    float* out = (float*)d_out;

    __bf16* ws  = (__bf16*)d_ws;
    __bf16* xb  = ws;
    __bf16* wqb = ws + (size_t)XN;
    __bf16* wob = wqb + (size_t)WQN;
    __bf16* qb  = wob + (size_t)WON;
    const size_t SZ = (size_t)Bdim * Hn * Nseq * HDim;
    __bf16* kb  = qb + SZ;
    __bf16* vt  = kb + SZ;
    __bf16* ao  = vt + SZ;

    convert_kernel<<<dim3(8192), dim3(256), 0, stream>>>(x, Wq, Wo, xb, wqb, wob);
    // (4096/32)*(3072/64) = 6144 waves -> 1536 blocks
    qkv_kernel<<<dim3(1536), dim3(256), 0, stream>>>(xb, wqb, bq, qb, kb, vt);
    // 32 bh * 128 qt = 4096 waves -> 1024 blocks (balanced qt mapping)
    attn_kernel<<<dim3(1024), dim3(256), 0, stream>>>(qb, kb, vt, ao);
    // (4096/32)*(1024/64) = 2048 waves -> 512 blocks
    proj_kernel<<<dim3(512), dim3(256), 0, stream>>>(ao, wob, bo, out);
}

// Round 6
// 270.915 us; speedup vs baseline: 2.2226x; 1.4576x over previous
//
#include <hip/hip_runtime.h>
#include <hip/hip_bf16.h>

// Problem constants
#define Bdim 2
#define Nseq 2048
#define Dmod 1024
#define Hn   16
#define HDim 64

#define XN  (Bdim * Nseq * Dmod)        // 4,194,304
#define WQN (3 * Dmod * Dmod)           // 3,145,728
#define WON (Dmod * Dmod)               // 1,048,576

typedef __attribute__((ext_vector_type(8))) __bf16 bf16x8;
typedef __attribute__((ext_vector_type(4))) __bf16 bf16x4;
typedef __attribute__((ext_vector_type(4))) float  floatx4;

__device__ __forceinline__ floatx4 mfma16(bf16x8 a, bf16x8 b, floatx4 c) {
    return __builtin_amdgcn_mfma_f32_16x16x32_bf16(a, b, c, 0, 0, 0);
}

// native v_exp_f32 computes 2^x
__device__ __forceinline__ float exp2v(float x) {
    return __builtin_amdgcn_exp2f(x);
}

// async global->LDS, 16 B per lane. LDS dest must be wave-uniform base +
// lane*16 (we pass base + tid*16 within a contiguous region -> satisfied).
__device__ __forceinline__ void async_copy16(__bf16* l, const __bf16* g) {
    __builtin_amdgcn_global_load_lds(
        (const __attribute__((address_space(1))) void*)g,
        (__attribute__((address_space(3))) void*)l,
        16, 0, 0);
}

// ---------------------------------------------------------------------------
// Kernel 0: fp32 -> bf16 conversion of x, W_qkv, W_out into workspace.
// ---------------------------------------------------------------------------
__global__ __launch_bounds__(256) void convert_kernel(
    const float* __restrict__ x, const float* __restrict__ wq,
    const float* __restrict__ wo,
    __bf16* __restrict__ xb, __bf16* __restrict__ wqb, __bf16* __restrict__ wob)
{
    int i = (blockIdx.x * 256 + threadIdx.x) * 4;
    const float* src;
    __bf16* dst;
    int off;
    if (i < XN)            { src = x;  dst = xb;  off = i; }
    else if (i < XN + WQN) { src = wq; dst = wqb; off = i - XN; }
    else                   { src = wo; dst = wob; off = i - XN - WQN; }
    float4 v = *(const float4*)(src + off);
    bf16x4 o;
    o.x = (__bf16)v.x; o.y = (__bf16)v.y; o.z = (__bf16)v.z; o.w = (__bf16)v.w;
    *(bf16x4*)(dst + off) = o;
}

// ---------------------------------------------------------------------------
// Kernel 1: QKV projection — m97-style 128x128 LDS-staged GEMM.
// Block: 256 thr = 4 waves; each wave one 64x64 quadrant (4x4 16x16 acc).
// K-loop BK=32: stage A 128x32 + B 128x32 (8 KB each) via global_load_lds
// width 16, lane-contiguous [128][32] layout (no padding).
// Epilogue scatters to Q [B,H,N,HD], K [B,H,N,HD], Vt [B,H,HD,N].
// ---------------------------------------------------------------------------
__global__ __launch_bounds__(256) void qkv_kernel(
    const __bf16* __restrict__ x, const __bf16* __restrict__ Wq,
    const float* __restrict__ bq,
    __bf16* __restrict__ qb, __bf16* __restrict__ kb, __bf16* __restrict__ vt)
{
    __shared__ __align__(16) __bf16 ldsA[128 * 32];
    __shared__ __align__(16) __bf16 ldsB[128 * 32];

    const int tid  = threadIdx.x;
    const int lane = tid & 63, l16 = lane & 15, quad = lane >> 4;
    const int wiw  = tid >> 6;
    const int wm   = wiw & 1, wn = wiw >> 1;

    const int bm = blockIdx.x & 31;             // 32 m-tiles (M=4096)
    const int bn = blockIdx.x >> 5;             // 24 n-tiles (N=3072)
    const int m0 = bm * 128, n0 = bn * 128;

    const int srow = tid >> 2;                  // staging row 0..63
    const int scol = (tid & 3) * 8;             // staging col {0,8,16,24}

    floatx4 z = {0.f, 0.f, 0.f, 0.f};
    floatx4 acc[4][4];
    #pragma unroll
    for (int mt = 0; mt < 4; ++mt)
        #pragma unroll
        for (int nt = 0; nt < 4; ++nt) acc[mt][nt] = z;

    const __bf16* ga = x  + (size_t)m0 * Dmod;
    const __bf16* gb = Wq + (size_t)n0 * Dmod;

    for (int k0 = 0; k0 < Dmod; k0 += 32) {
        async_copy16(&ldsA[srow * 32 + scol],        ga + (size_t)srow * Dmod + k0 + scol);
        async_copy16(&ldsA[(64 + srow) * 32 + scol], ga + (size_t)(64 + srow) * Dmod + k0 + scol);
        async_copy16(&ldsB[srow * 32 + scol],        gb + (size_t)srow * Dmod + k0 + scol);
        async_copy16(&ldsB[(64 + srow) * 32 + scol], gb + (size_t)(64 + srow) * Dmod + k0 + scol);
        __syncthreads();                         // compiler drains vmcnt before barrier

        bf16x8 af[4], bfr[4];
        #pragma unroll
        for (int mt = 0; mt < 4; ++mt)
            af[mt] = *(const bf16x8*)&ldsA[(wm * 64 + mt * 16 + l16) * 32 + quad * 8];
        #pragma unroll
        for (int nt = 0; nt < 4; ++nt)
            bfr[nt] = *(const bf16x8*)&ldsB[(wn * 64 + nt * 16 + l16) * 32 + quad * 8];
        #pragma unroll
        for (int mt = 0; mt < 4; ++mt)
            #pragma unroll
            for (int nt = 0; nt < 4; ++nt)
                acc[mt][nt] = mfma16(af[mt], bfr[nt], acc[mt][nt]);
        __syncthreads();
    }

    // Epilogue: wave n-base is 64-aligned -> single (which, head) per wave.
    const int nb    = n0 + wn * 64;
    const int which = nb >> 10;
    const int h     = (nb & 1023) >> 6;
    const int mw    = m0 + wm * 64;
    const int bi    = mw >> 11;
    const int pos0  = mw & (Nseq - 1);

    #pragma unroll
    for (int nt = 0; nt < 4; ++nt) {
        float bias = bq[nb + nt * 16 + l16];
        int hd = nt * 16 + l16;
        #pragma unroll
        for (int mt = 0; mt < 4; ++mt)
            #pragma unroll
            for (int i = 0; i < 4; ++i) {
                int pos = pos0 + mt * 16 + quad * 4 + i;   // C/D row = quad*4+i
                __bf16 v = (__bf16)(acc[mt][nt][i] + bias);
                if (which == 0)
                    qb[((bi * Hn + h) * Nseq + pos) * HDim + hd] = v;
                else if (which == 1)
                    kb[((bi * Hn + h) * Nseq + pos) * HDim + hd] = v;
                else
                    vt[((bi * Hn + h) * HDim + hd) * Nseq + pos] = v;
            }
    }
}

// ---------------------------------------------------------------------------
// Kernel 2: causal flash attention, S^T formulation (unchanged from R5).
// ---------------------------------------------------------------------------
__global__ __launch_bounds__(256) void attn_kernel(
    const __bf16* __restrict__ qbuf, const __bf16* __restrict__ kbuf,
    const __bf16* __restrict__ vtbuf, __bf16* __restrict__ aout)
{
    __shared__ __align__(16) __bf16 lds[4][16 * 72];

    const int tid  = threadIdx.x;
    const int wiw  = tid >> 6;
    const int lane = tid & 63, l16 = lane & 15, quad = lane >> 4;
    const int b    = blockIdx.x;
    const int bh   = b & 31;
    const int qt   = (b >> 5) + 32 * wiw;       // balanced causal work
    const int q0   = qt * 16;

    const __bf16* qs = qbuf  + bh * Nseq * HDim;
    const __bf16* ks = kbuf  + bh * Nseq * HDim;
    const __bf16* vs = vtbuf + bh * HDim * Nseq;

    bf16x8 qf0 = *(const bf16x8*)(qs + (q0 + l16) * HDim + quad * 8);
    bf16x8 qf1 = *(const bf16x8*)(qs + (q0 + l16) * HDim + 32 + quad * 8);

    floatx4 z = {0.f, 0.f, 0.f, 0.f};
    floatx4 o[4];
    #pragma unroll
    for (int s = 0; s < 4; ++s) o[s] = z;
    float m_i = -1e30f, l_i = 0.f;              // per-lane: q = q0 + l16

    const float C   = 0.125f * 1.44269504f;     // scale * log2(e)
    const int   nkt = (q0 >> 6) + 1;            // 64-key tiles
    __bf16* myp = lds[wiw];

    for (int kt = 0; kt < nkt; ++kt) {
        const int k0 = kt * 64;
        const bool last = (kt == nkt - 1);

        floatx4 st[4];
        #pragma unroll
        for (int t = 0; t < 4; ++t) {
            const __bf16* kp = ks + (k0 + t * 16 + l16) * HDim + quad * 8;
            bf16x8 kf0 = *(const bf16x8*)(kp);
            bf16x8 kf1 = *(const bf16x8*)(kp + 32);
            st[t] = mfma16(kf0, qf0, z);
            st[t] = mfma16(kf1, qf1, st[t]);
        }

        float a[16];
        #pragma unroll
        for (int t = 0; t < 4; ++t)
            #pragma unroll
            for (int i = 0; i < 4; ++i) {
                float v = st[t][i] * C;
                if (last) {
                    int key = k0 + t * 16 + quad * 4 + i;
                    v = (key <= q0 + l16) ? v : -1e30f;
                }
                a[t * 4 + i] = v;
            }

        float mx = a[0];
        #pragma unroll
        for (int j = 1; j < 16; ++j) mx = fmaxf(mx, a[j]);
        mx = fmaxf(mx, __shfl_xor(mx, 16));
        mx = fmaxf(mx, __shfl_xor(mx, 32));

        float mn    = fmaxf(m_i, mx);
        float alpha = exp2v(m_i - mn);

        float p[16], rs = 0.f;
        #pragma unroll
        for (int j = 0; j < 16; ++j) { p[j] = exp2v(a[j] - mn); rs += p[j]; }
        rs += __shfl_xor(rs, 16);
        rs += __shfl_xor(rs, 32);
        l_i = l_i * alpha + rs;
        m_i = mn;

        #pragma unroll
        for (int s = 0; s < 4; ++s)
            #pragma unroll
            for (int i = 0; i < 4; ++i) o[s][i] *= alpha;

        #pragma unroll
        for (int t = 0; t < 4; ++t) {
            bf16x4 pk;
            pk.x = (__bf16)p[t * 4 + 0]; pk.y = (__bf16)p[t * 4 + 1];
            pk.z = (__bf16)p[t * 4 + 2]; pk.w = (__bf16)p[t * 4 + 3];
            *(bf16x4*)(myp + l16 * 72 + t * 16 + quad * 4) = pk;
        }
        asm volatile("s_waitcnt lgkmcnt(0)" ::: "memory");
        bf16x8 pf0 = *(const bf16x8*)(myp + l16 * 72 + quad * 8);
        bf16x8 pf1 = *(const bf16x8*)(myp + l16 * 72 + 32 + quad * 8);

        #pragma unroll
        for (int s = 0; s < 4; ++s) {
            const __bf16* vp = vs + (s * 16 + l16) * Nseq + k0 + quad * 8;
            bf16x8 vf0 = *(const bf16x8*)(vp);
            bf16x8 vf1 = *(const bf16x8*)(vp + 32);
            o[s] = mfma16(vf0, pf0, o[s]);
            o[s] = mfma16(vf1, pf1, o[s]);
        }
    }

    const float inv = 1.0f / l_i;
    const int bi = bh >> 4, h = bh & 15;
    #pragma unroll
    for (int s = 0; s < 4; ++s) {
        bf16x4 ov;
        ov.x = (__bf16)(o[s][0] * inv); ov.y = (__bf16)(o[s][1] * inv);
        ov.z = (__bf16)(o[s][2] * inv); ov.w = (__bf16)(o[s][3] * inv);
        *(bf16x4*)(aout + ((size_t)(bi * Nseq + q0 + l16)) * Dmod
                   + h * 64 + s * 16 + quad * 4) = ov;
    }
}

// ---------------------------------------------------------------------------
// Kernel 3: output projection — same m97-style 128x128 LDS-staged GEMM,
// fp32 output + bias.
// ---------------------------------------------------------------------------
__global__ __launch_bounds__(256) void proj_kernel(
    const __bf16* __restrict__ ao, const __bf16* __restrict__ Wo,
    const float* __restrict__ bo, float* __restrict__ out)
{
    __shared__ __align__(16) __bf16 ldsA[128 * 32];
    __shared__ __align__(16) __bf16 ldsB[128 * 32];

    const int tid  = threadIdx.x;
    const int lane = tid & 63, l16 = lane & 15, quad = lane >> 4;
    const int wiw  = tid >> 6;
    const int wm   = wiw & 1, wn = wiw >> 1;

    const int bm = blockIdx.x & 31;             // 32 m-tiles (M=4096)
    const int bn = blockIdx.x >> 5;             // 8 n-tiles (N=1024)
    const int m0 = bm * 128, n0 = bn * 128;

    const int srow = tid >> 2;
    const int scol = (tid & 3) * 8;

    floatx4 z = {0.f, 0.f, 0.f, 0.f};
    floatx4 acc[4][4];
    #pragma unroll
    for (int mt = 0; mt < 4; ++mt)
        #pragma unroll
        for (int nt = 0; nt < 4; ++nt) acc[mt][nt] = z;

    const __bf16* ga = ao + (size_t)m0 * Dmod;
    const __bf16* gb = Wo + (size_t)n0 * Dmod;

    for (int k0 = 0; k0 < Dmod; k0 += 32) {
        async_copy16(&ldsA[srow * 32 + scol],        ga + (size_t)srow * Dmod + k0 + scol);
        async_copy16(&ldsA[(64 + srow) * 32 + scol], ga + (size_t)(64 + srow) * Dmod + k0 + scol);
        async_copy16(&ldsB[srow * 32 + scol],        gb + (size_t)srow * Dmod + k0 + scol);
        async_copy16(&ldsB[(64 + srow) * 32 + scol], gb + (size_t)(64 + srow) * Dmod + k0 + scol);
        __syncthreads();

        bf16x8 af[4], bfr[4];
        #pragma unroll
        for (int mt = 0; mt < 4; ++mt)
            af[mt] = *(const bf16x8*)&ldsA[(wm * 64 + mt * 16 + l16) * 32 + quad * 8];
        #pragma unroll
        for (int nt = 0; nt < 4; ++nt)
            bfr[nt] = *(const bf16x8*)&ldsB[(wn * 64 + nt * 16 + l16) * 32 + quad * 8];
        #pragma unroll
        for (int mt = 0; mt < 4; ++mt)
            #pragma unroll
            for (int nt = 0; nt < 4; ++nt)
                acc[mt][nt] = mfma16(af[mt], bfr[nt], acc[mt][nt]);
        __syncthreads();
    }

    const int nb = n0 + wn * 64;
    const int mw = m0 + wm * 64;
    #pragma unroll
    for (int nt = 0; nt < 4; ++nt) {
        float bias = bo[nb + nt * 16 + l16];
        #pragma unroll
        for (int mt = 0; mt < 4; ++mt)
            #pragma unroll
            for (int i = 0; i < 4; ++i) {
                int m = mw + mt * 16 + quad * 4 + i;
                out[(size_t)m * Dmod + nb + nt * 16 + l16] = acc[mt][nt][i] + bias;
            }
    }
}

// ---------------------------------------------------------------------------
extern "C" void kernel_launch(void* const* d_in, const int* in_sizes, int n_in,
                              void* d_out, int out_size, void* d_ws, size_t ws_size,
                              hipStream_t stream) {
    const float* x  = (const float*)d_in[0];
    const float* Wq = (const float*)d_in[1];
    const float* bq = (const float*)d_in[2];
    const float* Wo = (const float*)d_in[3];
    const float* bo = (const float*)d_in[4];
    float* out = (float*)d_out;

    __bf16* ws  = (__bf16*)d_ws;
    __bf16* xb  = ws;
    __bf16* wqb = ws + (size_t)XN;
    __bf16* wob = wqb + (size_t)WQN;
    __bf16* qb  = wob + (size_t)WON;
    const size_t SZ = (size_t)Bdim * Hn * Nseq * HDim;
    __bf16* kb  = qb + SZ;
    __bf16* vt  = kb + SZ;
    __bf16* ao  = vt + SZ;

    convert_kernel<<<dim3(8192), dim3(256), 0, stream>>>(x, Wq, Wo, xb, wqb, wob);
    // 32 m-tiles x 24 n-tiles = 768 blocks
    qkv_kernel<<<dim3(768), dim3(256), 0, stream>>>(xb, wqb, bq, qb, kb, vt);
    // 32 bh * 128 qt = 4096 waves -> 1024 blocks (balanced qt mapping)
    attn_kernel<<<dim3(1024), dim3(256), 0, stream>>>(qb, kb, vt, ao);
    // 32 m-tiles x 8 n-tiles = 256 blocks
    proj_kernel<<<dim3(256), dim3(256), 0, stream>>>(ao, wob, bo, out);
}

// Round 7
// 200.997 us; speedup vs baseline: 2.9957x; 1.3479x over previous
//
#include <hip/hip_runtime.h>
#include <hip/hip_bf16.h>

// Problem constants
#define Bdim 2
#define Nseq 2048
#define Dmod 1024
#define Hn   16
#define HDim 64

#define XN  (Bdim * Nseq * Dmod)        // 4,194,304
#define WQN (3 * Dmod * Dmod)           // 3,145,728
#define WON (Dmod * Dmod)               // 1,048,576

typedef __attribute__((ext_vector_type(8))) __bf16 bf16x8;
typedef __attribute__((ext_vector_type(4))) __bf16 bf16x4;
typedef __attribute__((ext_vector_type(4))) float  floatx4;

__device__ __forceinline__ floatx4 mfma16(bf16x8 a, bf16x8 b, floatx4 c) {
    return __builtin_amdgcn_mfma_f32_16x16x32_bf16(a, b, c, 0, 0, 0);
}

// native v_exp_f32 computes 2^x
__device__ __forceinline__ float exp2v(float x) {
    return __builtin_amdgcn_exp2f(x);
}

// async global->LDS, 16 B per lane. LDS dest must be wave-uniform base +
// lane*16 (we pass base + tid*16 within a contiguous region -> satisfied).
__device__ __forceinline__ void async_copy16(__bf16* l, const __bf16* g) {
    __builtin_amdgcn_global_load_lds(
        (const __attribute__((address_space(1))) void*)g,
        (__attribute__((address_space(3))) void*)l,
        16, 0, 0);
}

// ---------------------------------------------------------------------------
// Kernel 0: fp32 -> bf16 conversion of x, W_qkv, W_out into workspace.
// ---------------------------------------------------------------------------
__global__ __launch_bounds__(256) void convert_kernel(
    const float* __restrict__ x, const float* __restrict__ wq,
    const float* __restrict__ wo,
    __bf16* __restrict__ xb, __bf16* __restrict__ wqb, __bf16* __restrict__ wob)
{
    int i = (blockIdx.x * 256 + threadIdx.x) * 4;
    const float* src;
    __bf16* dst;
    int off;
    if (i < XN)            { src = x;  dst = xb;  off = i; }
    else if (i < XN + WQN) { src = wq; dst = wqb; off = i - XN; }
    else                   { src = wo; dst = wob; off = i - XN - WQN; }
    float4 v = *(const float4*)(src + off);
    bf16x4 o;
    o.x = (__bf16)v.x; o.y = (__bf16)v.y; o.z = (__bf16)v.z; o.w = (__bf16)v.w;
    *(bf16x4*)(dst + off) = o;
}

// ---------------------------------------------------------------------------
// Kernel 1: QKV projection — m97-style 128x128 LDS-staged GEMM. (unchanged)
// ---------------------------------------------------------------------------
__global__ __launch_bounds__(256) void qkv_kernel(
    const __bf16* __restrict__ x, const __bf16* __restrict__ Wq,
    const float* __restrict__ bq,
    __bf16* __restrict__ qb, __bf16* __restrict__ kb, __bf16* __restrict__ vt)
{
    __shared__ __align__(16) __bf16 ldsA[128 * 32];
    __shared__ __align__(16) __bf16 ldsB[128 * 32];

    const int tid  = threadIdx.x;
    const int lane = tid & 63, l16 = lane & 15, quad = lane >> 4;
    const int wiw  = tid >> 6;
    const int wm   = wiw & 1, wn = wiw >> 1;

    const int bm = blockIdx.x & 31;             // 32 m-tiles (M=4096)
    const int bn = blockIdx.x >> 5;             // 24 n-tiles (N=3072)
    const int m0 = bm * 128, n0 = bn * 128;

    const int srow = tid >> 2;                  // staging row 0..63
    const int scol = (tid & 3) * 8;             // staging col {0,8,16,24}

    floatx4 z = {0.f, 0.f, 0.f, 0.f};
    floatx4 acc[4][4];
    #pragma unroll
    for (int mt = 0; mt < 4; ++mt)
        #pragma unroll
        for (int nt = 0; nt < 4; ++nt) acc[mt][nt] = z;

    const __bf16* ga = x  + (size_t)m0 * Dmod;
    const __bf16* gb = Wq + (size_t)n0 * Dmod;

    for (int k0 = 0; k0 < Dmod; k0 += 32) {
        async_copy16(&ldsA[srow * 32 + scol],        ga + (size_t)srow * Dmod + k0 + scol);
        async_copy16(&ldsA[(64 + srow) * 32 + scol], ga + (size_t)(64 + srow) * Dmod + k0 + scol);
        async_copy16(&ldsB[srow * 32 + scol],        gb + (size_t)srow * Dmod + k0 + scol);
        async_copy16(&ldsB[(64 + srow) * 32 + scol], gb + (size_t)(64 + srow) * Dmod + k0 + scol);
        __syncthreads();

        bf16x8 af[4], bfr[4];
        #pragma unroll
        for (int mt = 0; mt < 4; ++mt)
            af[mt] = *(const bf16x8*)&ldsA[(wm * 64 + mt * 16 + l16) * 32 + quad * 8];
        #pragma unroll
        for (int nt = 0; nt < 4; ++nt)
            bfr[nt] = *(const bf16x8*)&ldsB[(wn * 64 + nt * 16 + l16) * 32 + quad * 8];
        #pragma unroll
        for (int mt = 0; mt < 4; ++mt)
            #pragma unroll
            for (int nt = 0; nt < 4; ++nt)
                acc[mt][nt] = mfma16(af[mt], bfr[nt], acc[mt][nt]);
        __syncthreads();
    }

    const int nb    = n0 + wn * 64;
    const int which = nb >> 10;
    const int h     = (nb & 1023) >> 6;
    const int mw    = m0 + wm * 64;
    const int bi    = mw >> 11;
    const int pos0  = mw & (Nseq - 1);

    #pragma unroll
    for (int nt = 0; nt < 4; ++nt) {
        float bias = bq[nb + nt * 16 + l16];
        int hd = nt * 16 + l16;
        #pragma unroll
        for (int mt = 0; mt < 4; ++mt)
            #pragma unroll
            for (int i = 0; i < 4; ++i) {
                int pos = pos0 + mt * 16 + quad * 4 + i;
                __bf16 v = (__bf16)(acc[mt][nt][i] + bias);
                if (which == 0)
                    qb[((bi * Hn + h) * Nseq + pos) * HDim + hd] = v;
                else if (which == 1)
                    kb[((bi * Hn + h) * Nseq + pos) * HDim + hd] = v;
                else
                    vt[((bi * Hn + h) * HDim + hd) * Nseq + pos] = v;
            }
    }
}

// ---------------------------------------------------------------------------
// Kernel 2: causal flash attention, block-cooperative.
// Block = (bh, 64-query tile): 4 waves = 4 consecutive 16-q subtiles.
// Per 64-key tile: K (64x64) and V^T (64x64) staged once into LDS via
// global_load_lds (m97 pattern), shared by all 4 waves. 64q || 64k alignment
// => all waves need exactly qb+1 tiles: zero waste, zero wave imbalance.
// S^T = K·Q^T softmax stays per-lane (R6-verified); P via per-wave LDS.
// Heavy-first: qb = 31 - (b>>5) so longest blocks dispatch first.
// ---------------------------------------------------------------------------
__global__ __launch_bounds__(256, 4) void attn_kernel(
    const __bf16* __restrict__ qbuf, const __bf16* __restrict__ kbuf,
    const __bf16* __restrict__ vtbuf, __bf16* __restrict__ aout)
{
    __shared__ __align__(16) __bf16 ldsK[64 * 64];   // [key][d]
    __shared__ __align__(16) __bf16 ldsV[64 * 64];   // [d][key]
    __shared__ __align__(16) __bf16 ldsP[4][16 * 72];

    const int tid  = threadIdx.x;
    const int wiw  = tid >> 6;
    const int lane = tid & 63, l16 = lane & 15, quad = lane >> 4;
    const int b    = blockIdx.x;
    const int bh   = b & 31;
    const int qb   = 31 - (b >> 5);             // 64-q block index, heavy first
    const int q0   = qb * 64 + wiw * 16;        // this wave's 16 queries

    const __bf16* qs = qbuf  + bh * Nseq * HDim;
    const __bf16* ks = kbuf  + bh * Nseq * HDim;
    const __bf16* vs = vtbuf + bh * HDim * Nseq;

    // staging split: each thread copies 16 B; rows 0..31 and 32..63
    const int srow = tid >> 3;                  // 0..31
    const int scol = (tid & 7) * 8;             // 0,8,...,56

    // Q as B-operand: lane l16 = q row, k = d = quad*8+j
    bf16x8 qf0 = *(const bf16x8*)(qs + (q0 + l16) * HDim + quad * 8);
    bf16x8 qf1 = *(const bf16x8*)(qs + (q0 + l16) * HDim + 32 + quad * 8);

    floatx4 z = {0.f, 0.f, 0.f, 0.f};
    floatx4 o[4];
    #pragma unroll
    for (int s = 0; s < 4; ++s) o[s] = z;
    float m_i = -1e30f, l_i = 0.f;              // per-lane: q = q0 + l16

    const float C   = 0.125f * 1.44269504f;     // scale * log2(e)
    const int   nkt = qb + 1;                   // 64-key tiles (same for all waves)
    __bf16* myp = ldsP[wiw];

    for (int kt = 0; kt < nkt; ++kt) {
        const int k0 = kt * 64;
        const bool last = (kt == nkt - 1);

        // Stage K[64][64] and V[64][64] for this tile (4 x 16B per thread).
        async_copy16(&ldsK[srow * 64 + scol],
                     ks + (size_t)(k0 + srow) * HDim + scol);
        async_copy16(&ldsK[(srow + 32) * 64 + scol],
                     ks + (size_t)(k0 + srow + 32) * HDim + scol);
        async_copy16(&ldsV[srow * 64 + scol],
                     vs + (size_t)srow * Nseq + k0 + scol);
        async_copy16(&ldsV[(srow + 32) * 64 + scol],
                     vs + (size_t)(srow + 32) * Nseq + k0 + scol);
        __syncthreads();                        // drains vmcnt; K/V visible

        // S^T: 4 subtiles of 16 keys. A=K (m=key), B=Q (n=q).
        floatx4 st[4];
        #pragma unroll
        for (int t = 0; t < 4; ++t) {
            bf16x8 kf0 = *(const bf16x8*)&ldsK[(t * 16 + l16) * 64 + quad * 8];
            bf16x8 kf1 = *(const bf16x8*)&ldsK[(t * 16 + l16) * 64 + 32 + quad * 8];
            st[t] = mfma16(kf0, qf0, z);
            st[t] = mfma16(kf1, qf1, st[t]);
        }

        // scores (log2 domain); lane holds keys {16t+quad*4+i} for q=q0+l16
        float a[16];
        #pragma unroll
        for (int t = 0; t < 4; ++t)
            #pragma unroll
            for (int i = 0; i < 4; ++i) {
                float v = st[t][i] * C;
                if (last) {
                    int kidx = t * 16 + quad * 4 + i;      // key - k0
                    v = (kidx <= wiw * 16 + l16) ? v : -1e30f;
                }
                a[t * 4 + i] = v;
            }

        float mx = a[0];
        #pragma unroll
        for (int j = 1; j < 16; ++j) mx = fmaxf(mx, a[j]);
        mx = fmaxf(mx, __shfl_xor(mx, 16));
        mx = fmaxf(mx, __shfl_xor(mx, 32));

        float mn    = fmaxf(m_i, mx);
        float alpha = exp2v(m_i - mn);

        float p[16], rs = 0.f;
        #pragma unroll
        for (int j = 0; j < 16; ++j) { p[j] = exp2v(a[j] - mn); rs += p[j]; }
        rs += __shfl_xor(rs, 16);
        rs += __shfl_xor(rs, 32);
        l_i = l_i * alpha + rs;
        m_i = mn;

        #pragma unroll
        for (int s = 0; s < 4; ++s)
            #pragma unroll
            for (int i = 0; i < 4; ++i) o[s][i] *= alpha;

        // P: C-layout -> LDS -> B-layout (per-wave region)
        #pragma unroll
        for (int t = 0; t < 4; ++t) {
            bf16x4 pk;
            pk.x = (__bf16)p[t * 4 + 0]; pk.y = (__bf16)p[t * 4 + 1];
            pk.z = (__bf16)p[t * 4 + 2]; pk.w = (__bf16)p[t * 4 + 3];
            *(bf16x4*)(myp + l16 * 72 + t * 16 + quad * 4) = pk;
        }
        asm volatile("s_waitcnt lgkmcnt(0)" ::: "memory");
        bf16x8 pf0 = *(const bf16x8*)(myp + l16 * 72 + quad * 8);
        bf16x8 pf1 = *(const bf16x8*)(myp + l16 * 72 + 32 + quad * 8);

        // O^T += V^T P^T : A=V^T (m=d, k=key) from LDS
        #pragma unroll
        for (int s = 0; s < 4; ++s) {
            bf16x8 vf0 = *(const bf16x8*)&ldsV[(s * 16 + l16) * 64 + quad * 8];
            bf16x8 vf1 = *(const bf16x8*)&ldsV[(s * 16 + l16) * 64 + 32 + quad * 8];
            o[s] = mfma16(vf0, pf0, o[s]);
            o[s] = mfma16(vf1, pf1, o[s]);
        }
        __syncthreads();                        // all waves done with K/V tile
    }

    // Epilogue: O^T tile s: row = d = s*16+quad*4+i, col = q = q0+l16
    const float inv = 1.0f / l_i;
    const int bi = bh >> 4, h = bh & 15;
    #pragma unroll
    for (int s = 0; s < 4; ++s) {
        bf16x4 ov;
        ov.x = (__bf16)(o[s][0] * inv); ov.y = (__bf16)(o[s][1] * inv);
        ov.z = (__bf16)(o[s][2] * inv); ov.w = (__bf16)(o[s][3] * inv);
        *(bf16x4*)(aout + ((size_t)(bi * Nseq + q0 + l16)) * Dmod
                   + h * 64 + s * 16 + quad * 4) = ov;
    }
}

// ---------------------------------------------------------------------------
// Kernel 3: output projection — m97-style 128x128 LDS-staged GEMM. (unchanged)
// ---------------------------------------------------------------------------
__global__ __launch_bounds__(256) void proj_kernel(
    const __bf16* __restrict__ ao, const __bf16* __restrict__ Wo,
    const float* __restrict__ bo, float* __restrict__ out)
{
    __shared__ __align__(16) __bf16 ldsA[128 * 32];
    __shared__ __align__(16) __bf16 ldsB[128 * 32];

    const int tid  = threadIdx.x;
    const int lane = tid & 63, l16 = lane & 15, quad = lane >> 4;
    const int wiw  = tid >> 6;
    const int wm   = wiw & 1, wn = wiw >> 1;

    const int bm = blockIdx.x & 31;             // 32 m-tiles (M=4096)
    const int bn = blockIdx.x >> 5;             // 8 n-tiles (N=1024)
    const int m0 = bm * 128, n0 = bn * 128;

    const int srow = tid >> 2;
    const int scol = (tid & 3) * 8;

    floatx4 z = {0.f, 0.f, 0.f, 0.f};
    floatx4 acc[4][4];
    #pragma unroll
    for (int mt = 0; mt < 4; ++mt)
        #pragma unroll
        for (int nt = 0; nt < 4; ++nt) acc[mt][nt] = z;

    const __bf16* ga = ao + (size_t)m0 * Dmod;
    const __bf16* gb = Wo + (size_t)n0 * Dmod;

    for (int k0 = 0; k0 < Dmod; k0 += 32) {
        async_copy16(&ldsA[srow * 32 + scol],        ga + (size_t)srow * Dmod + k0 + scol);
        async_copy16(&ldsA[(64 + srow) * 32 + scol], ga + (size_t)(64 + srow) * Dmod + k0 + scol);
        async_copy16(&ldsB[srow * 32 + scol],        gb + (size_t)srow * Dmod + k0 + scol);
        async_copy16(&ldsB[(64 + srow) * 32 + scol], gb + (size_t)(64 + srow) * Dmod + k0 + scol);
        __syncthreads();

        bf16x8 af[4], bfr[4];
        #pragma unroll
        for (int mt = 0; mt < 4; ++mt)
            af[mt] = *(const bf16x8*)&ldsA[(wm * 64 + mt * 16 + l16) * 32 + quad * 8];
        #pragma unroll
        for (int nt = 0; nt < 4; ++nt)
            bfr[nt] = *(const bf16x8*)&ldsB[(wn * 64 + nt * 16 + l16) * 32 + quad * 8];
        #pragma unroll
        for (int mt = 0; mt < 4; ++mt)
            #pragma unroll
            for (int nt = 0; nt < 4; ++nt)
                acc[mt][nt] = mfma16(af[mt], bfr[nt], acc[mt][nt]);
        __syncthreads();
    }

    const int nb = n0 + wn * 64;
    const int mw = m0 + wm * 64;
    #pragma unroll
    for (int nt = 0; nt < 4; ++nt) {
        float bias = bo[nb + nt * 16 + l16];
        #pragma unroll
        for (int mt = 0; mt < 4; ++mt)
            #pragma unroll
            for (int i = 0; i < 4; ++i) {
                int m = mw + mt * 16 + quad * 4 + i;
                out[(size_t)m * Dmod + nb + nt * 16 + l16] = acc[mt][nt][i] + bias;
            }
    }
}

// ---------------------------------------------------------------------------
extern "C" void kernel_launch(void* const* d_in, const int* in_sizes, int n_in,
                              void* d_out, int out_size, void* d_ws, size_t ws_size,
                              hipStream_t stream) {
    const float* x  = (const float*)d_in[0];
    const float* Wq = (const float*)d_in[1];
    const float* bq = (const float*)d_in[2];
    const float* Wo = (const float*)d_in[3];
    const float* bo = (const float*)d_in[4];
    float* out = (float*)d_out;

    __bf16* ws  = (__bf16*)d_ws;
    __bf16* xb  = ws;
    __bf16* wqb = ws + (size_t)XN;
    __bf16* wob = wqb + (size_t)WQN;
    __bf16* qb  = wob + (size_t)WON;
    const size_t SZ = (size_t)Bdim * Hn * Nseq * HDim;
    __bf16* kb  = qb + SZ;
    __bf16* vt  = kb + SZ;
    __bf16* ao  = vt + SZ;

    convert_kernel<<<dim3(8192), dim3(256), 0, stream>>>(x, Wq, Wo, xb, wqb, wob);
    // 32 m-tiles x 24 n-tiles = 768 blocks
    qkv_kernel<<<dim3(768), dim3(256), 0, stream>>>(xb, wqb, bq, qb, kb, vt);
    // 32 bh x 32 q-blocks = 1024 blocks, 4 waves each (block-cooperative)
    attn_kernel<<<dim3(1024), dim3(256), 0, stream>>>(qb, kb, vt, ao);
    // 32 m-tiles x 8 n-tiles = 256 blocks
    proj_kernel<<<dim3(256), dim3(256), 0, stream>>>(ao, wob, bo, out);
}

// Round 8
// 188.248 us; speedup vs baseline: 3.1986x; 1.0677x over previous
//
#include <hip/hip_runtime.h>
#include <hip/hip_bf16.h>

// Problem constants
#define Bdim 2
#define Nseq 2048
#define Dmod 1024
#define Hn   16
#define HDim 64

#define XN  (Bdim * Nseq * Dmod)        // 4,194,304
#define WQN (3 * Dmod * Dmod)           // 3,145,728
#define WON (Dmod * Dmod)               // 1,048,576

typedef __attribute__((ext_vector_type(8))) __bf16 bf16x8;
typedef __attribute__((ext_vector_type(4))) __bf16 bf16x4;
typedef __attribute__((ext_vector_type(4))) float  floatx4;

__device__ __forceinline__ floatx4 mfma16(bf16x8 a, bf16x8 b, floatx4 c) {
    return __builtin_amdgcn_mfma_f32_16x16x32_bf16(a, b, c, 0, 0, 0);
}

// native v_exp_f32 computes 2^x
__device__ __forceinline__ float exp2v(float x) {
    return __builtin_amdgcn_exp2f(x);
}

// async global->LDS, 16 B per lane (GEMMs only; attn uses swizzled ds_write).
__device__ __forceinline__ void async_copy16(__bf16* l, const __bf16* g) {
    __builtin_amdgcn_global_load_lds(
        (const __attribute__((address_space(1))) void*)g,
        (__attribute__((address_space(3))) void*)l,
        16, 0, 0);
}

// ---------------------------------------------------------------------------
// Kernel 0: fp32 -> bf16 conversion of x, W_qkv, W_out into workspace.
// ---------------------------------------------------------------------------
__global__ __launch_bounds__(256) void convert_kernel(
    const float* __restrict__ x, const float* __restrict__ wq,
    const float* __restrict__ wo,
    __bf16* __restrict__ xb, __bf16* __restrict__ wqb, __bf16* __restrict__ wob)
{
    int i = (blockIdx.x * 256 + threadIdx.x) * 4;
    const float* src;
    __bf16* dst;
    int off;
    if (i < XN)            { src = x;  dst = xb;  off = i; }
    else if (i < XN + WQN) { src = wq; dst = wqb; off = i - XN; }
    else                   { src = wo; dst = wob; off = i - XN - WQN; }
    float4 v = *(const float4*)(src + off);
    bf16x4 o;
    o.x = (__bf16)v.x; o.y = (__bf16)v.y; o.z = (__bf16)v.z; o.w = (__bf16)v.w;
    *(bf16x4*)(dst + off) = o;
}

// ---------------------------------------------------------------------------
// Kernel 1: QKV projection — m97-style 128x128 LDS-staged GEMM. (unchanged)
// ---------------------------------------------------------------------------
__global__ __launch_bounds__(256) void qkv_kernel(
    const __bf16* __restrict__ x, const __bf16* __restrict__ Wq,
    const float* __restrict__ bq,
    __bf16* __restrict__ qb, __bf16* __restrict__ kb, __bf16* __restrict__ vt)
{
    __shared__ __align__(16) __bf16 ldsA[128 * 32];
    __shared__ __align__(16) __bf16 ldsB[128 * 32];

    const int tid  = threadIdx.x;
    const int lane = tid & 63, l16 = lane & 15, quad = lane >> 4;
    const int wiw  = tid >> 6;
    const int wm   = wiw & 1, wn = wiw >> 1;

    const int bm = blockIdx.x & 31;             // 32 m-tiles (M=4096)
    const int bn = blockIdx.x >> 5;             // 24 n-tiles (N=3072)
    const int m0 = bm * 128, n0 = bn * 128;

    const int srow = tid >> 2;                  // staging row 0..63
    const int scol = (tid & 3) * 8;             // staging col {0,8,16,24}

    floatx4 z = {0.f, 0.f, 0.f, 0.f};
    floatx4 acc[4][4];
    #pragma unroll
    for (int mt = 0; mt < 4; ++mt)
        #pragma unroll
        for (int nt = 0; nt < 4; ++nt) acc[mt][nt] = z;

    const __bf16* ga = x  + (size_t)m0 * Dmod;
    const __bf16* gb = Wq + (size_t)n0 * Dmod;

    for (int k0 = 0; k0 < Dmod; k0 += 32) {
        async_copy16(&ldsA[srow * 32 + scol],        ga + (size_t)srow * Dmod + k0 + scol);
        async_copy16(&ldsA[(64 + srow) * 32 + scol], ga + (size_t)(64 + srow) * Dmod + k0 + scol);
        async_copy16(&ldsB[srow * 32 + scol],        gb + (size_t)srow * Dmod + k0 + scol);
        async_copy16(&ldsB[(64 + srow) * 32 + scol], gb + (size_t)(64 + srow) * Dmod + k0 + scol);
        __syncthreads();

        bf16x8 af[4], bfr[4];
        #pragma unroll
        for (int mt = 0; mt < 4; ++mt)
            af[mt] = *(const bf16x8*)&ldsA[(wm * 64 + mt * 16 + l16) * 32 + quad * 8];
        #pragma unroll
        for (int nt = 0; nt < 4; ++nt)
            bfr[nt] = *(const bf16x8*)&ldsB[(wn * 64 + nt * 16 + l16) * 32 + quad * 8];
        #pragma unroll
        for (int mt = 0; mt < 4; ++mt)
            #pragma unroll
            for (int nt = 0; nt < 4; ++nt)
                acc[mt][nt] = mfma16(af[mt], bfr[nt], acc[mt][nt]);
        __syncthreads();
    }

    const int nb    = n0 + wn * 64;
    const int which = nb >> 10;
    const int h     = (nb & 1023) >> 6;
    const int mw    = m0 + wm * 64;
    const int bi    = mw >> 11;
    const int pos0  = mw & (Nseq - 1);

    #pragma unroll
    for (int nt = 0; nt < 4; ++nt) {
        float bias = bq[nb + nt * 16 + l16];
        int hd = nt * 16 + l16;
        #pragma unroll
        for (int mt = 0; mt < 4; ++mt)
            #pragma unroll
            for (int i = 0; i < 4; ++i) {
                int pos = pos0 + mt * 16 + quad * 4 + i;
                __bf16 v = (__bf16)(acc[mt][nt][i] + bias);
                if (which == 0)
                    qb[((bi * Hn + h) * Nseq + pos) * HDim + hd] = v;
                else if (which == 1)
                    kb[((bi * Hn + h) * Nseq + pos) * HDim + hd] = v;
                else
                    vt[((bi * Hn + h) * HDim + hd) * Nseq + pos] = v;
            }
    }
}

// ---------------------------------------------------------------------------
// Kernel 2: causal flash attention, block-cooperative.
// Block = (bh, 64-query tile): 4 waves = 4 consecutive 16-q subtiles.
// K (64x64) and V^T (64x64) staged once per 64-key tile into LDS with an
// XOR block-swizzle (physical 16B block = b ^ (row&7)) -> conflict-free
// ds_read_b128 fragment reads. Staging is register-prefetched one tile
// ahead (global->VGPR->ds_write), hiding L2 latency outside the barrier.
// S^T = K·Q^T per-lane softmax (R6-verified); P via per-wave LDS region.
// Heavy-first: qblk = 31 - (b>>5) so longest blocks dispatch first.
// ---------------------------------------------------------------------------
__global__ __launch_bounds__(256, 4) void attn_kernel(
    const __bf16* __restrict__ qbuf, const __bf16* __restrict__ kbuf,
    const __bf16* __restrict__ vtbuf, __bf16* __restrict__ aout)
{
    __shared__ __align__(16) __bf16 ldsK[64 * 64];   // [key][d], swizzled
    __shared__ __align__(16) __bf16 ldsV[64 * 64];   // [d][key], swizzled
    __shared__ __align__(16) __bf16 ldsP[4][16 * 72];

    const int tid  = threadIdx.x;
    const int wiw  = tid >> 6;
    const int lane = tid & 63, l16 = lane & 15, quad = lane >> 4;
    const int b    = blockIdx.x;
    const int bh   = b & 31;
    const int qblk = 31 - (b >> 5);             // 64-q block index, heavy first
    const int q0   = qblk * 64 + wiw * 16;      // this wave's 16 queries

    const __bf16* qs = qbuf  + bh * Nseq * HDim;
    const __bf16* ks = kbuf  + bh * Nseq * HDim;
    const __bf16* vs = vtbuf + bh * HDim * Nseq;

    // staging coords: thread handles rows sr, sr+32; 16B block sb
    const int sr  = tid >> 3;                   // 0..31
    const int sb  = tid & 7;                    // 0..7
    const int swr = (sb ^ (sr & 7)) * 8;        // swizzled block offset (elems)
    const int wk0 = sr * 64 + swr;              // (sr+32)&7 == sr&7
    const int wk1 = (sr + 32) * 64 + swr;

    // Q as B-operand: lane l16 = q row, k = d = quad*8+j
    bf16x8 qf0 = *(const bf16x8*)(qs + (q0 + l16) * HDim + quad * 8);
    bf16x8 qf1 = *(const bf16x8*)(qs + (q0 + l16) * HDim + 32 + quad * 8);

    floatx4 z = {0.f, 0.f, 0.f, 0.f};
    floatx4 o[4];
    #pragma unroll
    for (int s = 0; s < 4; ++s) o[s] = z;
    float m_i = -1e30f, l_i = 0.f;              // per-lane: q = q0 + l16

    const float C   = 0.125f * 1.44269504f;     // scale * log2(e)
    const int   nkt = qblk + 1;                 // 64-key tiles (uniform in block)
    __bf16* myp = ldsP[wiw];
    const int swz = l16 & 7;                    // read-side swizzle (row&7)

    // prefetch tile 0 into registers
    float4 rk0 = *(const float4*)(ks + (size_t)sr * HDim + sb * 8);
    float4 rk1 = *(const float4*)(ks + (size_t)(sr + 32) * HDim + sb * 8);
    float4 rv0 = *(const float4*)(vs + (size_t)sr * Nseq + sb * 8);
    float4 rv1 = *(const float4*)(vs + (size_t)(sr + 32) * Nseq + sb * 8);

    for (int kt = 0; kt < nkt; ++kt) {
        // issue next tile's global loads first (in flight during compute)
        float4 nk0 = {}, nk1 = {}, nv0 = {}, nv1 = {};
        if (kt + 1 < nkt) {
            const int k0n = (kt + 1) * 64;
            nk0 = *(const float4*)(ks + (size_t)(k0n + sr) * HDim + sb * 8);
            nk1 = *(const float4*)(ks + (size_t)(k0n + sr + 32) * HDim + sb * 8);
            nv0 = *(const float4*)(vs + (size_t)sr * Nseq + k0n + sb * 8);
            nv1 = *(const float4*)(vs + (size_t)(sr + 32) * Nseq + k0n + sb * 8);
        }

        // write current tile to LDS (swizzled)
        *(float4*)&ldsK[wk0] = rk0;
        *(float4*)&ldsK[wk1] = rk1;
        *(float4*)&ldsV[wk0] = rv0;
        *(float4*)&ldsV[wk1] = rv1;
        __syncthreads();

        const bool last = (kt == nkt - 1);

        // S^T: 4 subtiles of 16 keys. A=K (m=key), B=Q (n=q).
        floatx4 st[4];
        #pragma unroll
        for (int t = 0; t < 4; ++t) {
            const __bf16* kr = &ldsK[(t * 16 + l16) * 64];
            bf16x8 kf0 = *(const bf16x8*)(kr + ((quad ^ swz) * 8));
            bf16x8 kf1 = *(const bf16x8*)(kr + (((quad + 4) ^ swz) * 8));
            st[t] = mfma16(kf0, qf0, z);
            st[t] = mfma16(kf1, qf1, st[t]);
        }

        // scores (log2 domain); lane holds keys {16t+quad*4+i} for q=q0+l16
        float a[16];
        #pragma unroll
        for (int t = 0; t < 4; ++t)
            #pragma unroll
            for (int i = 0; i < 4; ++i) {
                float v = st[t][i] * C;
                if (last) {
                    int kidx = t * 16 + quad * 4 + i;      // key - k0
                    v = (kidx <= wiw * 16 + l16) ? v : -1e30f;
                }
                a[t * 4 + i] = v;
            }

        // row max: depth-4 tree + 2 cross-quad shuffles
        float mA = fmaxf(fmaxf(a[0], a[1]),  fmaxf(a[2], a[3]));
        float mB = fmaxf(fmaxf(a[4], a[5]),  fmaxf(a[6], a[7]));
        float mC = fmaxf(fmaxf(a[8], a[9]),  fmaxf(a[10], a[11]));
        float mD = fmaxf(fmaxf(a[12], a[13]), fmaxf(a[14], a[15]));
        float mx = fmaxf(fmaxf(mA, mB), fmaxf(mC, mD));
        mx = fmaxf(mx, __shfl_xor(mx, 16));
        mx = fmaxf(mx, __shfl_xor(mx, 32));

        float mn    = fmaxf(m_i, mx);
        float alpha = exp2v(m_i - mn);

        float p[16];
        #pragma unroll
        for (int j = 0; j < 16; ++j) p[j] = exp2v(a[j] - mn);
        float sA = (p[0] + p[1]) + (p[2] + p[3]);
        float sB = (p[4] + p[5]) + (p[6] + p[7]);
        float sC = (p[8] + p[9]) + (p[10] + p[11]);
        float sD = (p[12] + p[13]) + (p[14] + p[15]);
        float rs = (sA + sB) + (sC + sD);
        rs += __shfl_xor(rs, 16);
        rs += __shfl_xor(rs, 32);
        l_i = l_i * alpha + rs;
        m_i = mn;

        #pragma unroll
        for (int s = 0; s < 4; ++s)
            #pragma unroll
            for (int i = 0; i < 4; ++i) o[s][i] *= alpha;

        // P: C-layout -> LDS -> B-layout (per-wave region, stride 72)
        #pragma unroll
        for (int t = 0; t < 4; ++t) {
            bf16x4 pk;
            pk.x = (__bf16)p[t * 4 + 0]; pk.y = (__bf16)p[t * 4 + 1];
            pk.z = (__bf16)p[t * 4 + 2]; pk.w = (__bf16)p[t * 4 + 3];
            *(bf16x4*)(myp + l16 * 72 + t * 16 + quad * 4) = pk;
        }
        asm volatile("s_waitcnt lgkmcnt(0)" ::: "memory");
        bf16x8 pf0 = *(const bf16x8*)(myp + l16 * 72 + quad * 8);
        bf16x8 pf1 = *(const bf16x8*)(myp + l16 * 72 + 32 + quad * 8);

        // O^T += V^T P^T : A=V^T (m=d, k=key) from LDS (swizzled)
        #pragma unroll
        for (int s = 0; s < 4; ++s) {
            const __bf16* vr = &ldsV[(s * 16 + l16) * 64];
            bf16x8 vf0 = *(const bf16x8*)(vr + ((quad ^ swz) * 8));
            bf16x8 vf1 = *(const bf16x8*)(vr + (((quad + 4) ^ swz) * 8));
            o[s] = mfma16(vf0, pf0, o[s]);
            o[s] = mfma16(vf1, pf1, o[s]);
        }
        __syncthreads();                        // all waves done with K/V tile

        rk0 = nk0; rk1 = nk1; rv0 = nv0; rv1 = nv1;
    }

    // Epilogue: O^T tile s: row = d = s*16+quad*4+i, col = q = q0+l16
    const float inv = 1.0f / l_i;
    const int bi = bh >> 4, h = bh & 15;
    #pragma unroll
    for (int s = 0; s < 4; ++s) {
        bf16x4 ov;
        ov.x = (__bf16)(o[s][0] * inv); ov.y = (__bf16)(o[s][1] * inv);
        ov.z = (__bf16)(o[s][2] * inv); ov.w = (__bf16)(o[s][3] * inv);
        *(bf16x4*)(aout + ((size_t)(bi * Nseq + q0 + l16)) * Dmod
                   + h * 64 + s * 16 + quad * 4) = ov;
    }
}

// ---------------------------------------------------------------------------
// Kernel 3: output projection — m97-style 128x128 LDS-staged GEMM. (unchanged)
// ---------------------------------------------------------------------------
__global__ __launch_bounds__(256) void proj_kernel(
    const __bf16* __restrict__ ao, const __bf16* __restrict__ Wo,
    const float* __restrict__ bo, float* __restrict__ out)
{
    __shared__ __align__(16) __bf16 ldsA[128 * 32];
    __shared__ __align__(16) __bf16 ldsB[128 * 32];

    const int tid  = threadIdx.x;
    const int lane = tid & 63, l16 = lane & 15, quad = lane >> 4;
    const int wiw  = tid >> 6;
    const int wm   = wiw & 1, wn = wiw >> 1;

    const int bm = blockIdx.x & 31;             // 32 m-tiles (M=4096)
    const int bn = blockIdx.x >> 5;             // 8 n-tiles (N=1024)
    const int m0 = bm * 128, n0 = bn * 128;

    const int srow = tid >> 2;
    const int scol = (tid & 3) * 8;

    floatx4 z = {0.f, 0.f, 0.f, 0.f};
    floatx4 acc[4][4];
    #pragma unroll
    for (int mt = 0; mt < 4; ++mt)
        #pragma unroll
        for (int nt = 0; nt < 4; ++nt) acc[mt][nt] = z;

    const __bf16* ga = ao + (size_t)m0 * Dmod;
    const __bf16* gb = Wo + (size_t)n0 * Dmod;

    for (int k0 = 0; k0 < Dmod; k0 += 32) {
        async_copy16(&ldsA[srow * 32 + scol],        ga + (size_t)srow * Dmod + k0 + scol);
        async_copy16(&ldsA[(64 + srow) * 32 + scol], ga + (size_t)(64 + srow) * Dmod + k0 + scol);
        async_copy16(&ldsB[srow * 32 + scol],        gb + (size_t)srow * Dmod + k0 + scol);
        async_copy16(&ldsB[(64 + srow) * 32 + scol], gb + (size_t)(64 + srow) * Dmod + k0 + scol);
        __syncthreads();

        bf16x8 af[4], bfr[4];
        #pragma unroll
        for (int mt = 0; mt < 4; ++mt)
            af[mt] = *(const bf16x8*)&ldsA[(wm * 64 + mt * 16 + l16) * 32 + quad * 8];
        #pragma unroll
        for (int nt = 0; nt < 4; ++nt)
            bfr[nt] = *(const bf16x8*)&ldsB[(wn * 64 + nt * 16 + l16) * 32 + quad * 8];
        #pragma unroll
        for (int mt = 0; mt < 4; ++mt)
            #pragma unroll
            for (int nt = 0; nt < 4; ++nt)
                acc[mt][nt] = mfma16(af[mt], bfr[nt], acc[mt][nt]);
        __syncthreads();
    }

    const int nb = n0 + wn * 64;
    const int mw = m0 + wm * 64;
    #pragma unroll
    for (int nt = 0; nt < 4; ++nt) {
        float bias = bo[nb + nt * 16 + l16];
        #pragma unroll
        for (int mt = 0; mt < 4; ++mt)
            #pragma unroll
            for (int i = 0; i < 4; ++i) {
                int m = mw + mt * 16 + quad * 4 + i;
                out[(size_t)m * Dmod + nb + nt * 16 + l16] = acc[mt][nt][i] + bias;
            }
    }
}

// ---------------------------------------------------------------------------
extern "C" void kernel_launch(void* const* d_in, const int* in_sizes, int n_in,
                              void* d_out, int out_size, void* d_ws, size_t ws_size,
                              hipStream_t stream) {
    const float* x  = (const float*)d_in[0];
    const float* Wq = (const float*)d_in[1];
    const float* bq = (const float*)d_in[2];
    const float* Wo = (const float*)d_in[3];
    const float* bo = (const float*)d_in[4];
    float* out = (float*)d_out;

    __bf16* ws  = (__bf16*)d_ws;
    __bf16* xb  = ws;
    __bf16* wqb = ws + (size_t)XN;
    __bf16* wob = wqb + (size_t)WQN;
    __bf16* qb  = wob + (size_t)WON;
    const size_t SZ = (size_t)Bdim * Hn * Nseq * HDim;
    __bf16* kb  = qb + SZ;
    __bf16* vt  = kb + SZ;
    __bf16* ao  = vt + SZ;

    convert_kernel<<<dim3(8192), dim3(256), 0, stream>>>(x, Wq, Wo, xb, wqb, wob);
    // 32 m-tiles x 24 n-tiles = 768 blocks
    qkv_kernel<<<dim3(768), dim3(256), 0, stream>>>(xb, wqb, bq, qb, kb, vt);
    // 32 bh x 32 q-blocks = 1024 blocks, 4 waves each (block-cooperative)
    attn_kernel<<<dim3(1024), dim3(256), 0, stream>>>(qb, kb, vt, ao);
    // 32 m-tiles x 8 n-tiles = 256 blocks
    proj_kernel<<<dim3(256), dim3(256), 0, stream>>>(ao, wob, bo, out);
}